// Round 2
// baseline (358.517 us; speedup 1.0000x reference)
//
#include <hip/hip_runtime.h>

#define DEVFN __device__ __forceinline__

// NaN-propagating relu (fmaxf(NaN,0)==0 would mask upstream failures).
DEVFN float relu(float x) { return x < 0.f ? 0.f : x; }

// ---------------------------------------------------------------------------
// KA: fused pre-work, two block roles interleaved (bx%3): 2/3 src, 1/3 nbr.
//  src role : src = features@in_w+in_b + relu(pe)@pe_w2+pe_b2 ; qs/ks/vs
//  nbr role : neighbor top-16 (manhattan<=4, stable); nbr-block 0 zeros BN.
// q/k/v loop: register outer-product tile (4 rows x 2 cols x 3 mats) with
// 2-way K-split + LDS partial reduction: 4 LDS act reads + 12 float2 weight
// loads per 96 FMA (was 4 LDS + 12 scalar per 48 FMA).
// ---------------------------------------------------------------------------
__global__ __launch_bounds__(256, 4) void ka_pre_cst(
    const float* __restrict__ features, const int* __restrict__ coords,
    const float* __restrict__ pe_w1, const float* __restrict__ pe_b1,
    const float* __restrict__ pe_w2, const float* __restrict__ pe_b2,
    const float* __restrict__ in_w, const float* __restrict__ in_b,
    const float* __restrict__ q_w, const float* __restrict__ k_w,
    const float* __restrict__ v_w,
    float* __restrict__ src,
    float* __restrict__ qs, float* __restrict__ ks, float* __restrict__ vs,
    int* __restrict__ nbr, float* __restrict__ bnAcc, int N)
{
    // src-role LDS
    __shared__ __align__(16) float sF[512];   // 8 rows x 64 features
    __shared__ __align__(16) float sH[512];   // 8 rows x 64 pe-hidden
    __shared__ __align__(16) float S[1024];   // 8 rows x 128 src
    __shared__ __align__(16) float sQP[1024]; // qkv K-split partials
    __shared__ __align__(16) float sKP[1024];
    __shared__ __align__(16) float sVP[1024];
    __shared__ int   sC[24];
    // nbr-role LDS
    __shared__ int cnt[16];
    __shared__ int lst[16 * 64];
    __shared__ int outL[256];

    const int tid = threadIdx.x;
    const int bx = blockIdx.x;
    const int role_nbr = (bx % 3) == 2;

    if (role_nbr) {
        // ---------------- nbr role: neighbor search -----------------------
        const int nb = bx / 3;
        const int q0 = nb * 16;
        if (nb == 0 && tid < 128) bnAcc[tid] = 0.f;
        if (tid < 16) cnt[tid] = 0;
        outL[tid] = -1;
        __syncthreads();
        int qx[16], qy[16], qz[16];
#pragma unroll
        for (int q = 0; q < 16; ++q) {
            qx[q] = coords[(q0 + q) * 3 + 0];
            qy[q] = coords[(q0 + q) * 3 + 1];
            qz[q] = coords[(q0 + q) * 3 + 2];
        }
        for (int cd = tid; cd < N; cd += 256) {
            int cx = coords[cd * 3 + 0];
            int cy = coords[cd * 3 + 1];
            int cz = coords[cd * 3 + 2];
#pragma unroll
            for (int q = 0; q < 16; ++q) {
                int dx = cx - qx[q]; dx = dx < 0 ? -dx : dx;
                int dy = cy - qy[q]; dy = dy < 0 ? -dy : dy;
                int dz = cz - qz[q]; dz = dz < 0 ? -dz : dz;
                int d = dx + dy + dz;
                if (d <= 4) {
                    int s = atomicAdd(&cnt[q], 1);
                    if (s < 64) lst[q * 64 + s] = (d << 13) | cd;
                }
            }
        }
        __syncthreads();
        {
            const int q = tid >> 4, t = tid & 15;
            int n = cnt[q]; if (n > 64) n = 64;
            for (int e = t; e < n; e += 16) {
                int key = lst[q * 64 + e];
                int rank = 0;
                for (int j = 0; j < n; ++j) rank += (lst[q * 64 + j] < key) ? 1 : 0;
                if (rank < 16) outL[q * 16 + rank] = key & 8191;
            }
        }
        __syncthreads();
        {
            const int q = tid >> 4, t = tid & 15;
            nbr[(q0 + q) * 16 + t] = outL[q * 16 + t];
        }
        return;
    }

    // ---------------- src role: src + q/k/v projections -------------------
    const int sb = (bx / 3) * 2 + (bx % 3);   // 0..1023
    const int r0 = sb * 8;
    if (tid < 24) sC[tid] = coords[r0 * 3 + tid];
    for (int i = tid; i < 512; i += 256) sF[i] = features[r0 * 64 + i];
    __syncthreads();
    for (int i = tid; i < 512; i += 256) {
        int r = i >> 6, t = i & 63;
        float v0 = sC[r * 3 + 0] * (1.f / 95.f);
        float v1 = sC[r * 3 + 1] * (1.f / 95.f);
        float v2 = sC[r * 3 + 2] * (1.f / 95.f);
        float h = v0 * pe_w1[t] + v1 * pe_w1[64 + t] + v2 * pe_w1[128 + t] + pe_b1[t];
        sH[i] = relu(h);
    }
    __syncthreads();
    {
        // src = sF @ in_w + sH @ pe_w2 + (in_b + pe_b2)
        const int c = tid & 127, rh = tid >> 7;
        float acc[4];
        const float base = in_b[c] + pe_b2[c];
#pragma unroll
        for (int r = 0; r < 4; ++r) acc[r] = base;
        const float* wi = in_w + c;
        const float* wp = pe_w2 + c;
        for (int j4 = 0; j4 < 16; ++j4) {
            float i0 = wi[(j4 * 4 + 0) * 128], i1 = wi[(j4 * 4 + 1) * 128];
            float i2 = wi[(j4 * 4 + 2) * 128], i3 = wi[(j4 * 4 + 3) * 128];
            float p0 = wp[(j4 * 4 + 0) * 128], p1 = wp[(j4 * 4 + 1) * 128];
            float p2 = wp[(j4 * 4 + 2) * 128], p3 = wp[(j4 * 4 + 3) * 128];
#pragma unroll
            for (int r = 0; r < 4; ++r) {
                const int rr = rh * 4 + r;
                float4 f = *(const float4*)(&sF[rr * 64 + j4 * 4]);
                float4 h = *(const float4*)(&sH[rr * 64 + j4 * 4]);
                acc[r] += f.x * i0 + f.y * i1 + f.z * i2 + f.w * i3
                        + h.x * p0 + h.y * p1 + h.z * p2 + h.w * p3;
            }
        }
#pragma unroll
        for (int r = 0; r < 4; ++r) {
            src[(r0 + rh * 4 + r) * 128 + c] = acc[r];
            S[(rh * 4 + r) * 128 + c] = acc[r];
        }
    }
    __syncthreads();
    // q/k/v: thread = (colpair cp, rowhalf rh2, khalf kh). 4 rows x 2 cols x
    // 3 mats register tile over K/2=64; partials reduced through LDS.
    {
        const int cp = tid & 63, rh2 = (tid >> 6) & 1, kh = tid >> 7;
        const int c0 = cp * 2, r0l = rh2 * 4, k0 = kh * 64;
        float aq[4][2], ak[4][2], av[4][2];
#pragma unroll
        for (int r = 0; r < 4; ++r)
            for (int cc = 0; cc < 2; ++cc) { aq[r][cc] = 0.f; ak[r][cc] = 0.f; av[r][cc] = 0.f; }
        for (int s = 0; s < 16; ++s) {
            const int kk = k0 + s * 4;
            float2 wq[4], wk[4], wv[4];
#pragma unroll
            for (int j = 0; j < 4; ++j) {
                wq[j] = *(const float2*)(q_w + (kk + j) * 128 + c0);
                wk[j] = *(const float2*)(k_w + (kk + j) * 128 + c0);
                wv[j] = *(const float2*)(v_w + (kk + j) * 128 + c0);
            }
#pragma unroll
            for (int r = 0; r < 4; ++r) {
                float4 s4 = *(const float4*)(&S[(r0l + r) * 128 + kk]);
                aq[r][0] += s4.x * wq[0].x + s4.y * wq[1].x + s4.z * wq[2].x + s4.w * wq[3].x;
                aq[r][1] += s4.x * wq[0].y + s4.y * wq[1].y + s4.z * wq[2].y + s4.w * wq[3].y;
                ak[r][0] += s4.x * wk[0].x + s4.y * wk[1].x + s4.z * wk[2].x + s4.w * wk[3].x;
                ak[r][1] += s4.x * wk[0].y + s4.y * wk[1].y + s4.z * wk[2].y + s4.w * wk[3].y;
                av[r][0] += s4.x * wv[0].x + s4.y * wv[1].x + s4.z * wv[2].x + s4.w * wv[3].x;
                av[r][1] += s4.x * wv[0].y + s4.y * wv[1].y + s4.z * wv[2].y + s4.w * wv[3].y;
            }
        }
        if (kh) {
#pragma unroll
            for (int r = 0; r < 4; ++r) {
                const int base = (r0l + r) * 128 + c0;
                *(float2*)(&sQP[base]) = make_float2(aq[r][0], aq[r][1]);
                *(float2*)(&sKP[base]) = make_float2(ak[r][0], ak[r][1]);
                *(float2*)(&sVP[base]) = make_float2(av[r][0], av[r][1]);
            }
        }
        __syncthreads();
        if (kh == 0) {
#pragma unroll
            for (int r = 0; r < 4; ++r) {
                const int base = (r0l + r) * 128 + c0;
                const int g = (r0 + r0l + r) * 128 + c0;
                float2 pq = *(const float2*)(&sQP[base]);
                float2 pk = *(const float2*)(&sKP[base]);
                float2 pv = *(const float2*)(&sVP[base]);
                *(float2*)(qs + g) = make_float2(aq[r][0] + pq.x, aq[r][1] + pq.y);
                *(float2*)(ks + g) = make_float2(ak[r][0] + pk.x, ak[r][1] + pk.y);
                *(float2*)(vs + g) = make_float2(av[r][0] + pv.x, av[r][1] + pv.y);
            }
        }
    }
}

// ---------------------------------------------------------------------------
// K4: attention + o-proj + LN1 + FFN + LN2 + fusion + BN partials.
// 8 rows/block, 1024 blocks. GEMM phases 2/3/4 use register outer-product
// tiles (4 rows x 4 cols per thread) with K-split; K-partials staged through
// dead LDS buffers and reduced by the kh==0 thread group. Per 64 FMA the
// inner step issues 4 LDS b128 broadcasts + 4 float4 weight loads (was
// 16 LDS + 8 scalar loads) -> ~4x less LDS-pipe, ~85% FMA density.
// ---------------------------------------------------------------------------
DEVFN void ln_rows8(float* Cb, const float* __restrict__ g,
                    const float* __restrict__ b, int tid)
{
    const int r = tid >> 5, l = tid & 31;
    float x[4]; float s = 0.f, s2 = 0.f;
#pragma unroll
    for (int i = 0; i < 4; ++i) {
        x[i] = Cb[r * 128 + l * 4 + i];
        s += x[i]; s2 += x[i] * x[i];
    }
#pragma unroll
    for (int o = 1; o < 32; o <<= 1) { s += __shfl_xor(s, o); s2 += __shfl_xor(s2, o); }
    float mu = s * (1.f / 128.f);
    float var = s2 * (1.f / 128.f) - mu * mu;
    float rstd = rsqrtf(var + 1e-5f);
#pragma unroll
    for (int i = 0; i < 4; ++i) {
        int cc = l * 4 + i;
        Cb[r * 128 + cc] = (x[i] - mu) * rstd * g[cc] + b[cc];
    }
}

__global__ __launch_bounds__(256, 4) void k4_main_cst(
    const float* __restrict__ features, const float* __restrict__ src,
    const float* __restrict__ qs, const float* __restrict__ ks, const float* __restrict__ vs,
    const int* __restrict__ nbr,
    const float* __restrict__ q_b, const float* __restrict__ k_b,
    const float* __restrict__ v_b,
    const float* __restrict__ o_w, const float* __restrict__ o_b,
    const float* __restrict__ n1_g, const float* __restrict__ n1_b,
    const float* __restrict__ l1_w, const float* __restrict__ l1_b,
    const float* __restrict__ l2_w, const float* __restrict__ l2_b,
    const float* __restrict__ n3_g, const float* __restrict__ n3_b,
    const float* __restrict__ fu_w, const float* __restrict__ fu_b,
    float* __restrict__ fused, float* __restrict__ bnSum, float* __restrict__ bnSq)
{
    __shared__ __align__(16) float A[1024];   // src tile / P3 partial rows0-3 / P4 partial kh=1
    __shared__ __align__(16) float Bt[1024];  // head_out / P3 partial rows4-7 / P4 partial kh=2
    __shared__ __align__(16) float C[1024];   // running activation
    __shared__ __align__(16) float Q[1024];   // q rows (bias applied) / P4 partial kh=3
    __shared__ __align__(16) float H[3072];   // P2 partials / ffn hidden / bn staging
    __shared__ __align__(16) float SC[512];   // attention scores
    __shared__ __align__(16) float F[512];    // features tile
    __shared__ __align__(16) float bK[128], bV[128];
    __shared__ int idxL[128];
    const int tid = threadIdx.x;
    const int r0 = blockIdx.x * 8;

    for (int i = tid; i < 1024; i += 256) A[i] = src[r0 * 128 + i];
    for (int i = tid; i < 512; i += 256) F[i] = features[r0 * 64 + i];
    if (tid < 128) {
        idxL[tid] = nbr[r0 * 16 + tid];
        bK[tid] = k_b[tid]; bV[tid] = v_b[tid];
    }
    __syncthreads();
    {   // vectorized Q gather + bias: thread = (row=tid>>5, colgroup=tid&31)
        int r = tid >> 5, cg = tid & 31;
        int i0 = idxL[r * 16];
        float4 qv = make_float4(0.f, 0.f, 0.f, 0.f);
        if (i0 >= 0) qv = *(const float4*)(qs + i0 * 128 + cg * 4);
        float4 qb = *(const float4*)(q_b + cg * 4);
        qv.x += qb.x; qv.y += qb.y; qv.z += qb.z; qv.w += qb.w;
        *(float4*)(&Q[r * 128 + cg * 4]) = qv;
    }
    __syncthreads();

    // ---- phase 1a: scores. thread = (row r, head h, group g of 8) --------
    const int ar = tid >> 5, ah = (tid >> 3) & 3, ag = tid & 7;
    {
#pragma unroll
        for (int jj = 0; jj < 2; ++jj) {
            int j = ag + jj * 8;
            int j4 = j >> 2, ch = j & 3;
            int id = idxL[ar * 16 + ah * 4 + j4];
            float s = 0.f;
#pragma unroll
            for (int c4 = 0; c4 < 8; ++c4) {
                float4 qv = *(const float4*)(&Q[ar * 128 + ah * 32 + c4 * 4]);
                float4 kb = *(const float4*)(&bK[ch * 32 + c4 * 4]);
                float4 kv = make_float4(0.f, 0.f, 0.f, 0.f);
                if (id >= 0) kv = *(const float4*)(ks + id * 128 + ch * 32 + c4 * 4);
                s += qv.x * (kv.x + kb.x) + qv.y * (kv.y + kb.y)
                   + qv.z * (kv.z + kb.z) + qv.w * (kv.w + kb.w);
            }
            SC[ar * 64 + ah * 16 + j] = s * 0.08838834764831845f;  // 1/sqrt(128)
        }
    }
    __syncthreads();

    // ---- phase 1b: softmax (redundant per 8-thread group) + P@V ----------
    {
        float p[16];
        float mx = -3.4e38f;
#pragma unroll
        for (int j = 0; j < 16; ++j) { p[j] = SC[ar * 64 + ah * 16 + j]; mx = fmaxf(mx, p[j]); }
        float sum = 0.f;
#pragma unroll
        for (int j = 0; j < 16; ++j) { p[j] = __expf(p[j] - mx); sum += p[j]; }
        float inv = 1.f / sum;
        float4 acc = make_float4(0.f, 0.f, 0.f, 0.f);
#pragma unroll
        for (int j = 0; j < 16; ++j) {
            int j4 = j >> 2, ch = j & 3;
            int id = idxL[ar * 16 + ah * 4 + j4];
            float4 vb = *(const float4*)(&bV[ch * 32 + ag * 4]);
            float4 vv = make_float4(0.f, 0.f, 0.f, 0.f);
            if (id >= 0) vv = *(const float4*)(vs + id * 128 + ch * 32 + ag * 4);
            float w = p[j] * inv;
            acc.x += w * (vv.x + vb.x); acc.y += w * (vv.y + vb.y);
            acc.z += w * (vv.z + vb.z); acc.w += w * (vv.w + vb.w);
        }
        *(float4*)(&Bt[ar * 128 + ah * 32 + ag * 4]) = acc;
    }
    __syncthreads();

    // ---- phase 2: out = head_out @ o_w; C = A + out + o_b; 4-way K-split -
    // thread = (cg=col/4 in 0..31, rg=rowhalf, kh=kquarter). acc 4x4.
    {
        const int cg = tid & 31, rg = (tid >> 5) & 1, kh = tid >> 6;
        const int c0 = cg * 4, r0l = rg * 4, k0 = kh * 32;
        float acc[4][4];
#pragma unroll
        for (int r = 0; r < 4; ++r)
            for (int cc = 0; cc < 4; ++cc) acc[r][cc] = 0.f;
        for (int s = 0; s < 8; ++s) {
            const int kk = k0 + s * 4;
            float4 w[4];
#pragma unroll
            for (int j = 0; j < 4; ++j) w[j] = *(const float4*)(o_w + (kk + j) * 128 + c0);
#pragma unroll
            for (int r = 0; r < 4; ++r) {
                float4 a = *(const float4*)(&Bt[(r0l + r) * 128 + kk]);
                acc[r][0] += a.x * w[0].x + a.y * w[1].x + a.z * w[2].x + a.w * w[3].x;
                acc[r][1] += a.x * w[0].y + a.y * w[1].y + a.z * w[2].y + a.w * w[3].y;
                acc[r][2] += a.x * w[0].z + a.y * w[1].z + a.z * w[2].z + a.w * w[3].z;
                acc[r][3] += a.x * w[0].w + a.y * w[1].w + a.z * w[2].w + a.w * w[3].w;
            }
        }
        if (kh) {
            float* dst = &H[(kh - 1) * 1024];
#pragma unroll
            for (int r = 0; r < 4; ++r)
                *(float4*)(&dst[(r0l + r) * 128 + c0]) =
                    make_float4(acc[r][0], acc[r][1], acc[r][2], acc[r][3]);
        }
        __syncthreads();
        if (kh == 0) {
            float4 ob = *(const float4*)(o_b + c0);
#pragma unroll
            for (int r = 0; r < 4; ++r) {
                const int base = (r0l + r) * 128 + c0;
                float4 av = *(const float4*)(&A[base]);
                float4 p0 = *(const float4*)(&H[base]);
                float4 p1 = *(const float4*)(&H[1024 + base]);
                float4 p2 = *(const float4*)(&H[2048 + base]);
                float4 cv;
                cv.x = av.x + ob.x + acc[r][0] + p0.x + p1.x + p2.x;
                cv.y = av.y + ob.y + acc[r][1] + p0.y + p1.y + p2.y;
                cv.z = av.z + ob.z + acc[r][2] + p0.z + p1.z + p2.z;
                cv.w = av.w + ob.w + acc[r][3] + p0.w + p1.w + p2.w;
                *(float4*)(&C[base]) = cv;
            }
        }
        __syncthreads();
    }
    ln_rows8(C, n1_g, n1_b, tid);   // C = tgt
    __syncthreads();

    // ---- phase 3: H = relu(C @ l1_w + l1_b)  [8 x 256]; 2-way K-split ----
    // thread = (cg in 0..63, rg, kh). Partials: rg0->A, rg1->Bt.
    {
        const int cg = tid & 63, rg = (tid >> 6) & 1, kh = tid >> 7;
        const int c0 = cg * 4, r0l = rg * 4, k0 = kh * 64;
        float acc[4][4];
#pragma unroll
        for (int r = 0; r < 4; ++r)
            for (int cc = 0; cc < 4; ++cc) acc[r][cc] = 0.f;
        for (int s = 0; s < 16; ++s) {
            const int kk = k0 + s * 4;
            float4 w[4];
#pragma unroll
            for (int j = 0; j < 4; ++j) w[j] = *(const float4*)(l1_w + (kk + j) * 256 + c0);
#pragma unroll
            for (int r = 0; r < 4; ++r) {
                float4 a = *(const float4*)(&C[(r0l + r) * 128 + kk]);
                acc[r][0] += a.x * w[0].x + a.y * w[1].x + a.z * w[2].x + a.w * w[3].x;
                acc[r][1] += a.x * w[0].y + a.y * w[1].y + a.z * w[2].y + a.w * w[3].y;
                acc[r][2] += a.x * w[0].z + a.y * w[1].z + a.z * w[2].z + a.w * w[3].z;
                acc[r][3] += a.x * w[0].w + a.y * w[1].w + a.z * w[2].w + a.w * w[3].w;
            }
        }
        float* PS = rg ? Bt : A;   // local rows 0..3, row stride 256
        if (kh) {
#pragma unroll
            for (int r = 0; r < 4; ++r)
                *(float4*)(&PS[r * 256 + c0]) =
                    make_float4(acc[r][0], acc[r][1], acc[r][2], acc[r][3]);
        }
        __syncthreads();
        if (kh == 0) {
            float4 lb = *(const float4*)(l1_b + c0);
#pragma unroll
            for (int r = 0; r < 4; ++r) {
                float4 p = *(const float4*)(&PS[r * 256 + c0]);
                float4 h;
                h.x = relu(acc[r][0] + p.x + lb.x);
                h.y = relu(acc[r][1] + p.y + lb.y);
                h.z = relu(acc[r][2] + p.z + lb.z);
                h.w = relu(acc[r][3] + p.w + lb.w);
                *(float4*)(&H[(r0l + r) * 256 + c0]) = h;
            }
        }
        __syncthreads();
    }

    // ---- phase 4: t2 = H @ l2_w; C += t2 + l2_b; 4-way K-split -----------
    // thread = (cg in 0..31, rg, kh). Partials kh=1,2,3 -> A, Bt, Q.
    {
        const int cg = tid & 31, rg = (tid >> 5) & 1, kh = tid >> 6;
        const int c0 = cg * 4, r0l = rg * 4, k0 = kh * 64;
        float acc[4][4];
#pragma unroll
        for (int r = 0; r < 4; ++r)
            for (int cc = 0; cc < 4; ++cc) acc[r][cc] = 0.f;
        for (int s = 0; s < 16; ++s) {
            const int kk = k0 + s * 4;
            float4 w[4];
#pragma unroll
            for (int j = 0; j < 4; ++j) w[j] = *(const float4*)(l2_w + (kk + j) * 128 + c0);
#pragma unroll
            for (int r = 0; r < 4; ++r) {
                float4 a = *(const float4*)(&H[(r0l + r) * 256 + kk]);
                acc[r][0] += a.x * w[0].x + a.y * w[1].x + a.z * w[2].x + a.w * w[3].x;
                acc[r][1] += a.x * w[0].y + a.y * w[1].y + a.z * w[2].y + a.w * w[3].y;
                acc[r][2] += a.x * w[0].z + a.y * w[1].z + a.z * w[2].z + a.w * w[3].z;
                acc[r][3] += a.x * w[0].w + a.y * w[1].w + a.z * w[2].w + a.w * w[3].w;
            }
        }
        if (kh) {
            float* dst = (kh == 1) ? A : ((kh == 2) ? Bt : Q);
#pragma unroll
            for (int r = 0; r < 4; ++r)
                *(float4*)(&dst[(r0l + r) * 128 + c0]) =
                    make_float4(acc[r][0], acc[r][1], acc[r][2], acc[r][3]);
        }
        __syncthreads();
        if (kh == 0) {
            float4 lb = *(const float4*)(l2_b + c0);
#pragma unroll
            for (int r = 0; r < 4; ++r) {
                const int base = (r0l + r) * 128 + c0;
                float4 cv = *(const float4*)(&C[base]);
                float4 p0 = *(const float4*)(&A[base]);
                float4 p1 = *(const float4*)(&Bt[base]);
                float4 p2 = *(const float4*)(&Q[base]);
                cv.x += lb.x + acc[r][0] + p0.x + p1.x + p2.x;
                cv.y += lb.y + acc[r][1] + p0.y + p1.y + p2.y;
                cv.z += lb.z + acc[r][2] + p0.z + p1.z + p2.z;
                cv.w += lb.w + acc[r][3] + p0.w + p1.w + p2.w;
                *(float4*)(&C[base]) = cv;
            }
        }
        __syncthreads();
    }
    ln_rows8(C, n3_g, n3_b, tid);   // C = final tgt
    __syncthreads();

    // ---- phase 5: fused = [F, C] @ fu_w + fu_b; BN partials --------------
    {
        const int c = tid & 63, rg = tid >> 6;
        float acc[2];
        const float fb = fu_b[c];
#pragma unroll
        for (int r = 0; r < 2; ++r) acc[r] = fb;
        const float* wA = fu_w + c;               // rows 0..63 (features half)
        for (int j4 = 0; j4 < 16; ++j4) {
            float w0 = wA[(j4 * 4 + 0) * 64], w1 = wA[(j4 * 4 + 1) * 64];
            float w2 = wA[(j4 * 4 + 2) * 64], w3 = wA[(j4 * 4 + 3) * 64];
#pragma unroll
            for (int r = 0; r < 2; ++r) {
                float4 t = *(const float4*)(&F[(rg * 2 + r) * 64 + j4 * 4]);
                acc[r] += t.x * w0 + t.y * w1 + t.z * w2 + t.w * w3;
            }
        }
        const float* wB = fu_w + 64 * 64 + c;     // rows 64..191 (tgt half)
        for (int j4 = 0; j4 < 32; ++j4) {
            float w0 = wB[(j4 * 4 + 0) * 64], w1 = wB[(j4 * 4 + 1) * 64];
            float w2 = wB[(j4 * 4 + 2) * 64], w3 = wB[(j4 * 4 + 3) * 64];
#pragma unroll
            for (int r = 0; r < 2; ++r) {
                float4 t = *(const float4*)(&C[(rg * 2 + r) * 128 + j4 * 4]);
                acc[r] += t.x * w0 + t.y * w1 + t.z * w2 + t.w * w3;
            }
        }
#pragma unroll
        for (int r = 0; r < 2; ++r) {
            int row = rg * 2 + r;
            float v = acc[r];
            fused[(r0 + row) * 64 + c] = v;
            H[row * 64 + c] = v;
        }
    }
    __syncthreads();
    if (tid < 64) {
        float s = 0.f, s2 = 0.f;
#pragma unroll
        for (int r = 0; r < 8; ++r) { float x = H[r * 64 + tid]; s += x; s2 += x * x; }
        atomicAdd(&bnSum[tid], s);
        atomicAdd(&bnSq[tid], s2);
    }
}

// ---------------------------------------------------------------------------
// K5: batchnorm (train-mode stats) + relu -> fp32 out
// ---------------------------------------------------------------------------
__global__ __launch_bounds__(256) void k5_bn_cst(
    const float* __restrict__ fused, const float* __restrict__ bnSum,
    const float* __restrict__ bnSq,
    const float* __restrict__ g, const float* __restrict__ b,
    float* __restrict__ out, int N)
{
    const int total = N * 64;
    const float invN = 1.f / (float)N;
    for (int i = blockIdx.x * 256 + threadIdx.x; i < total; i += gridDim.x * 256) {
        int c = i & 63;
        float mu = bnSum[c] * invN;
        float var = bnSq[c] * invN - mu * mu;
        float x = fused[i];
        float y = (x - mu) * rsqrtf(var + 1e-3f) * g[c] + b[c];
        out[i] = relu(y);
    }
}

// ---------------------------------------------------------------------------
extern "C" void kernel_launch(void* const* d_in, const int* in_sizes, int n_in,
                              void* d_out, int out_size, void* d_ws, size_t ws_size,
                              hipStream_t stream)
{
    const float* features = (const float*)d_in[0];
    const int*   coords   = (const int*)d_in[1];
    const float* pe_w1 = (const float*)d_in[2];
    const float* pe_b1 = (const float*)d_in[3];
    const float* pe_w2 = (const float*)d_in[4];
    const float* pe_b2 = (const float*)d_in[5];
    const float* in_w  = (const float*)d_in[6];
    const float* in_b  = (const float*)d_in[7];
    const float* q_w   = (const float*)d_in[8];
    const float* q_b   = (const float*)d_in[9];
    const float* k_w   = (const float*)d_in[10];
    const float* k_b   = (const float*)d_in[11];
    const float* v_w   = (const float*)d_in[12];
    const float* v_b   = (const float*)d_in[13];
    const float* o_w   = (const float*)d_in[14];
    const float* o_b   = (const float*)d_in[15];
    const float* n1_g  = (const float*)d_in[16];
    const float* n1_b  = (const float*)d_in[17];
    const float* l1_w  = (const float*)d_in[18];
    const float* l1_b  = (const float*)d_in[19];
    const float* l2_w  = (const float*)d_in[20];
    const float* l2_b  = (const float*)d_in[21];
    const float* n3_g  = (const float*)d_in[22];
    const float* n3_b  = (const float*)d_in[23];
    const float* fu_w  = (const float*)d_in[24];
    const float* fu_b  = (const float*)d_in[25];
    const float* bn_g  = (const float*)d_in[26];
    const float* bn_b  = (const float*)d_in[27];

    const int N = in_sizes[0] / 64;   // 8192

    float* src   = (float*)d_ws;            // N*128
    float* qs    = src + (size_t)N * 128;   // N*128
    float* ks    = qs  + (size_t)N * 128;   // N*128
    float* vs    = ks  + (size_t)N * 128;   // N*128
    float* fused = vs  + (size_t)N * 128;   // N*64
    int*   nbr    = (int*)(fused + (size_t)N * 64);   // N*16 ints
    float* bnSum  = (float*)(nbr + (size_t)N * 16);   // 64
    float* bnSq   = bnSum + 64;                       // 64 (contiguous 128)

    ka_pre_cst<<<N / 8 + N / 16, 256, 0, stream>>>(features, coords,
                                                   pe_w1, pe_b1, pe_w2, pe_b2,
                                                   in_w, in_b, q_w, k_w, v_w,
                                                   src, qs, ks, vs, nbr, bnSum, N);
    k4_main_cst<<<N / 8, 256, 0, stream>>>(features, src, qs, ks, vs, nbr,
                                           q_b, k_b, v_b, o_w, o_b, n1_g, n1_b,
                                           l1_w, l1_b, l2_w, l2_b, n3_g, n3_b,
                                           fu_w, fu_b, fused, bnSum, bnSq);
    k5_bn_cst<<<512, 256, 0, stream>>>(fused, bnSum, bnSq, bn_g, bn_b,
                                       (float*)d_out, N);
}

// Round 3
// 230.646 us; speedup vs baseline: 1.5544x; 1.5544x over previous
//
#include <hip/hip_runtime.h>

#define DEVFN __device__ __forceinline__

// NaN-propagating relu (fmaxf(NaN,0)==0 would mask upstream failures).
DEVFN float relu(float x) { return x < 0.f ? 0.f : x; }

// ---------------------------------------------------------------------------
// KA: fused pre-work, two block roles interleaved (bx%3): 2/3 src, 1/3 nbr.
//  src role : src = features@in_w+in_b + relu(pe)@pe_w2+pe_b2 ; qs/ks/vs
//  nbr role : neighbor top-16 (manhattan<=4, stable); nbr-block 0 zeros BN.
// (round-0 version: the 1-deep manual prefetch variant measured slightly
//  WORSE (70 vs <66 us) — compiler already schedules these loads.)
// ---------------------------------------------------------------------------
__global__ __launch_bounds__(256, 4) void ka_pre_cst(
    const float* __restrict__ features, const int* __restrict__ coords,
    const float* __restrict__ pe_w1, const float* __restrict__ pe_b1,
    const float* __restrict__ pe_w2, const float* __restrict__ pe_b2,
    const float* __restrict__ in_w, const float* __restrict__ in_b,
    const float* __restrict__ q_w, const float* __restrict__ k_w,
    const float* __restrict__ v_w,
    float* __restrict__ src,
    float* __restrict__ qs, float* __restrict__ ks, float* __restrict__ vs,
    int* __restrict__ nbr, float* __restrict__ bnAcc, int N)
{
    // src-role LDS
    __shared__ float sF[512];   // 8 rows x 64 features
    __shared__ float sH[512];   // 8 rows x 64 pe-hidden
    __shared__ float S[1024];   // 8 rows x 128 src
    __shared__ int   sC[24];
    // nbr-role LDS
    __shared__ int cnt[16];
    __shared__ int lst[16 * 64];
    __shared__ int outL[256];

    const int tid = threadIdx.x;
    const int bx = blockIdx.x;
    const int role_nbr = (bx % 3) == 2;

    if (role_nbr) {
        // ---------------- nbr role: neighbor search -----------------------
        const int nb = bx / 3;
        const int q0 = nb * 16;
        if (nb == 0 && tid < 128) bnAcc[tid] = 0.f;
        if (tid < 16) cnt[tid] = 0;
        outL[tid] = -1;
        __syncthreads();
        int qx[16], qy[16], qz[16];
#pragma unroll
        for (int q = 0; q < 16; ++q) {
            qx[q] = coords[(q0 + q) * 3 + 0];
            qy[q] = coords[(q0 + q) * 3 + 1];
            qz[q] = coords[(q0 + q) * 3 + 2];
        }
        for (int cd = tid; cd < N; cd += 256) {
            int cx = coords[cd * 3 + 0];
            int cy = coords[cd * 3 + 1];
            int cz = coords[cd * 3 + 2];
#pragma unroll
            for (int q = 0; q < 16; ++q) {
                int dx = cx - qx[q]; dx = dx < 0 ? -dx : dx;
                int dy = cy - qy[q]; dy = dy < 0 ? -dy : dy;
                int dz = cz - qz[q]; dz = dz < 0 ? -dz : dz;
                int d = dx + dy + dz;
                if (d <= 4) {
                    int s = atomicAdd(&cnt[q], 1);
                    if (s < 64) lst[q * 64 + s] = (d << 13) | cd;
                }
            }
        }
        __syncthreads();
        {
            const int q = tid >> 4, t = tid & 15;
            int n = cnt[q]; if (n > 64) n = 64;
            for (int e = t; e < n; e += 16) {
                int key = lst[q * 64 + e];
                int rank = 0;
                for (int j = 0; j < n; ++j) rank += (lst[q * 64 + j] < key) ? 1 : 0;
                if (rank < 16) outL[q * 16 + rank] = key & 8191;
            }
        }
        __syncthreads();
        {
            const int q = tid >> 4, t = tid & 15;
            nbr[(q0 + q) * 16 + t] = outL[q * 16 + t];
        }
        return;
    }

    // ---------------- src role: src + q/k/v projections -------------------
    const int sb = (bx / 3) * 2 + (bx % 3);   // 0..1023
    const int r0 = sb * 8;
    if (tid < 24) sC[tid] = coords[r0 * 3 + tid];
    for (int i = tid; i < 512; i += 256) sF[i] = features[r0 * 64 + i];
    __syncthreads();
    for (int i = tid; i < 512; i += 256) {
        int r = i >> 6, t = i & 63;
        float v0 = sC[r * 3 + 0] * (1.f / 95.f);
        float v1 = sC[r * 3 + 1] * (1.f / 95.f);
        float v2 = sC[r * 3 + 2] * (1.f / 95.f);
        float h = v0 * pe_w1[t] + v1 * pe_w1[64 + t] + v2 * pe_w1[128 + t] + pe_b1[t];
        sH[i] = relu(h);
    }
    __syncthreads();
    const int c = tid & 127, rh = tid >> 7;
    {
        float acc[4];
        const float base = in_b[c] + pe_b2[c];
#pragma unroll
        for (int r = 0; r < 4; ++r) acc[r] = base;
        for (int j = 0; j < 64; ++j) {
            float w1 = in_w[j * 128 + c];
            float w2 = pe_w2[j * 128 + c];
#pragma unroll
            for (int r = 0; r < 4; ++r) {
                int rr = rh * 4 + r;
                acc[r] += sF[rr * 64 + j] * w1 + sH[rr * 64 + j] * w2;
            }
        }
#pragma unroll
        for (int r = 0; r < 4; ++r) {
            src[(r0 + rh * 4 + r) * 128 + c] = acc[r];
            S[(rh * 4 + r) * 128 + c] = acc[r];
        }
    }
    __syncthreads();
    // q/k/v in one pass: 12 concurrent weight streams for latency hiding
    {
        float aq[4], ak[4], av[4];
#pragma unroll
        for (int r = 0; r < 4; ++r) { aq[r] = 0.f; ak[r] = 0.f; av[r] = 0.f; }
        for (int k4 = 0; k4 < 32; ++k4) {
            float wq0 = q_w[(k4 * 4 + 0) * 128 + c];
            float wq1 = q_w[(k4 * 4 + 1) * 128 + c];
            float wq2 = q_w[(k4 * 4 + 2) * 128 + c];
            float wq3 = q_w[(k4 * 4 + 3) * 128 + c];
            float wk0 = k_w[(k4 * 4 + 0) * 128 + c];
            float wk1 = k_w[(k4 * 4 + 1) * 128 + c];
            float wk2 = k_w[(k4 * 4 + 2) * 128 + c];
            float wk3 = k_w[(k4 * 4 + 3) * 128 + c];
            float wv0 = v_w[(k4 * 4 + 0) * 128 + c];
            float wv1 = v_w[(k4 * 4 + 1) * 128 + c];
            float wv2 = v_w[(k4 * 4 + 2) * 128 + c];
            float wv3 = v_w[(k4 * 4 + 3) * 128 + c];
#pragma unroll
            for (int r = 0; r < 4; ++r) {
                float4 s = *(const float4*)(&S[(rh * 4 + r) * 128 + k4 * 4]);
                aq[r] += s.x * wq0 + s.y * wq1 + s.z * wq2 + s.w * wq3;
                ak[r] += s.x * wk0 + s.y * wk1 + s.z * wk2 + s.w * wk3;
                av[r] += s.x * wv0 + s.y * wv1 + s.z * wv2 + s.w * wv3;
            }
        }
#pragma unroll
        for (int r = 0; r < 4; ++r) {
            qs[(r0 + rh * 4 + r) * 128 + c] = aq[r];
            ks[(r0 + rh * 4 + r) * 128 + c] = ak[r];
            vs[(r0 + rh * 4 + r) * 128 + c] = av[r];
        }
    }
}

// ---------------------------------------------------------------------------
// K4: attention + o-proj + LN1 + FFN + LN2 + fusion + BN partials.
// 8 rows/block, 1024 blocks (4/CU). GEMM phases 2/3/4: register outer-product
// tiles + K-split, partials reduced through dead LDS buffers. Accumulators
// are NAMED float4s (guaranteed SROA) and every K-loop carries
// `#pragma unroll 1`: round-2 showed full unroll hoists 16x4 float4 weight
// loads, spills acc to scratch (+300 MB scratch writes, 3x slower).
// LDS-pipe instrs/thread in P2/P3/P4: 576 -> 160 (the round-0 bottleneck:
// ~740 ds_read_b128/thread x 16 waves/CU x ~12cy ~= the whole 66 us).
// ---------------------------------------------------------------------------
DEVFN void ln_rows8(float* Cb, const float* __restrict__ g,
                    const float* __restrict__ b, int tid)
{
    const int r = tid >> 5, l = tid & 31;
    float x[4]; float s = 0.f, s2 = 0.f;
#pragma unroll
    for (int i = 0; i < 4; ++i) {
        x[i] = Cb[r * 128 + l * 4 + i];
        s += x[i]; s2 += x[i] * x[i];
    }
#pragma unroll
    for (int o = 1; o < 32; o <<= 1) { s += __shfl_xor(s, o); s2 += __shfl_xor(s2, o); }
    float mu = s * (1.f / 128.f);
    float var = s2 * (1.f / 128.f) - mu * mu;
    float rstd = rsqrtf(var + 1e-5f);
#pragma unroll
    for (int i = 0; i < 4; ++i) {
        int cc = l * 4 + i;
        Cb[r * 128 + cc] = (x[i] - mu) * rstd * g[cc] + b[cc];
    }
}

// fma helper: acc.{x,y,z,w} += a.{x..w} dot columns of w0..w3
DEVFN void op4(float4& acc, const float4 a,
               const float4 w0, const float4 w1, const float4 w2, const float4 w3)
{
    acc.x += a.x * w0.x + a.y * w1.x + a.z * w2.x + a.w * w3.x;
    acc.y += a.x * w0.y + a.y * w1.y + a.z * w2.y + a.w * w3.y;
    acc.z += a.x * w0.z + a.y * w1.z + a.z * w2.z + a.w * w3.z;
    acc.w += a.x * w0.w + a.y * w1.w + a.z * w2.w + a.w * w3.w;
}
DEVFN float4 f4add(float4 a, float4 b)
{ return make_float4(a.x + b.x, a.y + b.y, a.z + b.z, a.w + b.w); }

__global__ __launch_bounds__(256, 4) void k4_main_cst(
    const float* __restrict__ features, const float* __restrict__ src,
    const float* __restrict__ qs, const float* __restrict__ ks, const float* __restrict__ vs,
    const int* __restrict__ nbr,
    const float* __restrict__ q_b, const float* __restrict__ k_b,
    const float* __restrict__ v_b,
    const float* __restrict__ o_w, const float* __restrict__ o_b,
    const float* __restrict__ n1_g, const float* __restrict__ n1_b,
    const float* __restrict__ l1_w, const float* __restrict__ l1_b,
    const float* __restrict__ l2_w, const float* __restrict__ l2_b,
    const float* __restrict__ n3_g, const float* __restrict__ n3_b,
    const float* __restrict__ fu_w, const float* __restrict__ fu_b,
    float* __restrict__ fused, float* __restrict__ bnSum, float* __restrict__ bnSq)
{
    __shared__ __align__(16) float A[1024];   // src tile / P3 partial rows0-3 / P4 partial kq=1
    __shared__ __align__(16) float Bt[1024];  // head_out / P3 partial rows4-7 / P4 partial kq=2
    __shared__ __align__(16) float C[1024];   // running activation
    __shared__ __align__(16) float Q[1024];   // q rows (bias applied) / P4 partial kq=3
    __shared__ __align__(16) float H[2048];   // P2 partial (1024) / ffn hidden / bn staging
    __shared__ __align__(16) float SC[512];   // attention scores
    __shared__ __align__(16) float F[512];    // features tile
    __shared__ __align__(16) float bK[128], bV[128];
    __shared__ int idxL[128];
    const int tid = threadIdx.x;
    const int r0 = blockIdx.x * 8;

    for (int i = tid; i < 1024; i += 256) A[i] = src[r0 * 128 + i];
    for (int i = tid; i < 512; i += 256) F[i] = features[r0 * 64 + i];
    if (tid < 128) {
        idxL[tid] = nbr[r0 * 16 + tid];
        bK[tid] = k_b[tid]; bV[tid] = v_b[tid];
    }
    __syncthreads();
    {   // vectorized Q gather + bias: thread = (row=tid>>5, colgroup=tid&31)
        int r = tid >> 5, cg = tid & 31;
        int i0 = idxL[r * 16];
        float4 qv = make_float4(0.f, 0.f, 0.f, 0.f);
        if (i0 >= 0) qv = *(const float4*)(qs + i0 * 128 + cg * 4);
        float4 qb = *(const float4*)(q_b + cg * 4);
        qv.x += qb.x; qv.y += qb.y; qv.z += qb.z; qv.w += qb.w;
        *(float4*)(&Q[r * 128 + cg * 4]) = qv;
    }
    __syncthreads();

    // ---- phase 1a: scores. thread = (row r, head h, group g of 8) --------
    const int ar = tid >> 5, ah = (tid >> 3) & 3, ag = tid & 7;
    {
#pragma unroll
        for (int jj = 0; jj < 2; ++jj) {
            int j = ag + jj * 8;
            int j4 = j >> 2, ch = j & 3;
            int id = idxL[ar * 16 + ah * 4 + j4];
            float s = 0.f;
#pragma unroll
            for (int c4 = 0; c4 < 8; ++c4) {
                float4 qv = *(const float4*)(&Q[ar * 128 + ah * 32 + c4 * 4]);
                float4 kb = *(const float4*)(&bK[ch * 32 + c4 * 4]);
                float4 kv = make_float4(0.f, 0.f, 0.f, 0.f);
                if (id >= 0) kv = *(const float4*)(ks + id * 128 + ch * 32 + c4 * 4);
                s += qv.x * (kv.x + kb.x) + qv.y * (kv.y + kb.y)
                   + qv.z * (kv.z + kb.z) + qv.w * (kv.w + kb.w);
            }
            SC[ar * 64 + ah * 16 + j] = s * 0.08838834764831845f;  // 1/sqrt(128)
        }
    }
    __syncthreads();

    // ---- phase 1b: softmax (redundant per 8-thread group) + P@V ----------
    {
        float p[16];
        float mx = -3.4e38f;
#pragma unroll
        for (int j = 0; j < 16; ++j) { p[j] = SC[ar * 64 + ah * 16 + j]; mx = fmaxf(mx, p[j]); }
        float sum = 0.f;
#pragma unroll
        for (int j = 0; j < 16; ++j) { p[j] = __expf(p[j] - mx); sum += p[j]; }
        float inv = 1.f / sum;
        float4 acc = make_float4(0.f, 0.f, 0.f, 0.f);
#pragma unroll
        for (int j = 0; j < 16; ++j) {
            int j4 = j >> 2, ch = j & 3;
            int id = idxL[ar * 16 + ah * 4 + j4];
            float4 vb = *(const float4*)(&bV[ch * 32 + ag * 4]);
            float4 vv = make_float4(0.f, 0.f, 0.f, 0.f);
            if (id >= 0) vv = *(const float4*)(vs + id * 128 + ch * 32 + ag * 4);
            float w = p[j] * inv;
            acc.x += w * (vv.x + vb.x); acc.y += w * (vv.y + vb.y);
            acc.z += w * (vv.z + vb.z); acc.w += w * (vv.w + vb.w);
        }
        *(float4*)(&Bt[ar * 128 + ah * 32 + ag * 4]) = acc;
    }
    __syncthreads();

    // ---- phase 2: out = head_out @ o_w; C = A + out + o_b ----------------
    // thread = (cg 0..31 -> 4 cols, rp 0..3 -> 2 rows, kh 0..1 -> K-half).
    {
        const int cg = tid & 31, rp = (tid >> 5) & 3, kh = tid >> 7;
        const int c0 = cg * 4, r0l = rp * 2, k0 = kh * 64;
        float4 ac0 = make_float4(0.f, 0.f, 0.f, 0.f);
        float4 ac1 = make_float4(0.f, 0.f, 0.f, 0.f);
#pragma unroll 1
        for (int s = 0; s < 16; ++s) {
            const int kk = k0 + s * 4;
            const float* wp = o_w + kk * 128 + c0;
            float4 w0 = *(const float4*)(wp);
            float4 w1 = *(const float4*)(wp + 128);
            float4 w2 = *(const float4*)(wp + 256);
            float4 w3 = *(const float4*)(wp + 384);
            float4 a0 = *(const float4*)(&Bt[(r0l + 0) * 128 + kk]);
            float4 a1 = *(const float4*)(&Bt[(r0l + 1) * 128 + kk]);
            op4(ac0, a0, w0, w1, w2, w3);
            op4(ac1, a1, w0, w1, w2, w3);
        }
        if (kh) {
            *(float4*)(&H[(r0l + 0) * 128 + c0]) = ac0;
            *(float4*)(&H[(r0l + 1) * 128 + c0]) = ac1;
        }
        __syncthreads();
        if (kh == 0) {
            float4 ob = *(const float4*)(o_b + c0);
#pragma unroll
            for (int r = 0; r < 2; ++r) {
                const int base = (r0l + r) * 128 + c0;
                float4 av = *(const float4*)(&A[base]);
                float4 ph = *(const float4*)(&H[base]);
                float4 me = r ? ac1 : ac0;
                float4 cv;
                cv.x = av.x + ob.x + me.x + ph.x;
                cv.y = av.y + ob.y + me.y + ph.y;
                cv.z = av.z + ob.z + me.z + ph.z;
                cv.w = av.w + ob.w + me.w + ph.w;
                *(float4*)(&C[base]) = cv;
            }
        }
        __syncthreads();
    }
    ln_rows8(C, n1_g, n1_b, tid);   // C = tgt
    __syncthreads();

    // ---- phase 3: H = relu(C @ l1_w + l1_b)  [8 x 256] -------------------
    // thread = (cg 0..63 -> 4 cols, rh 0..1 -> 4 rows, kh 0..1 -> K-half).
    // Partials: rh0 -> A, rh1 -> Bt (local row stride 256).
    {
        const int cg = tid & 63, rh = (tid >> 6) & 1, kh = tid >> 7;
        const int c0 = cg * 4, r0l = rh * 4, k0 = kh * 64;
        float4 ac0 = make_float4(0.f, 0.f, 0.f, 0.f);
        float4 ac1 = make_float4(0.f, 0.f, 0.f, 0.f);
        float4 ac2 = make_float4(0.f, 0.f, 0.f, 0.f);
        float4 ac3 = make_float4(0.f, 0.f, 0.f, 0.f);
#pragma unroll 1
        for (int s = 0; s < 16; ++s) {
            const int kk = k0 + s * 4;
            const float* wp = l1_w + kk * 256 + c0;
            float4 w0 = *(const float4*)(wp);
            float4 w1 = *(const float4*)(wp + 256);
            float4 w2 = *(const float4*)(wp + 512);
            float4 w3 = *(const float4*)(wp + 768);
            float4 a0 = *(const float4*)(&C[(r0l + 0) * 128 + kk]);
            float4 a1 = *(const float4*)(&C[(r0l + 1) * 128 + kk]);
            float4 a2 = *(const float4*)(&C[(r0l + 2) * 128 + kk]);
            float4 a3 = *(const float4*)(&C[(r0l + 3) * 128 + kk]);
            op4(ac0, a0, w0, w1, w2, w3);
            op4(ac1, a1, w0, w1, w2, w3);
            op4(ac2, a2, w0, w1, w2, w3);
            op4(ac3, a3, w0, w1, w2, w3);
        }
        float* PS = rh ? Bt : A;
        if (kh) {
            *(float4*)(&PS[0 * 256 + c0]) = ac0;
            *(float4*)(&PS[1 * 256 + c0]) = ac1;
            *(float4*)(&PS[2 * 256 + c0]) = ac2;
            *(float4*)(&PS[3 * 256 + c0]) = ac3;
        }
        __syncthreads();
        if (kh == 0) {
            float4 lb = *(const float4*)(l1_b + c0);
#pragma unroll
            for (int r = 0; r < 4; ++r) {
                float4 p = *(const float4*)(&PS[r * 256 + c0]);
                float4 me = (r == 0) ? ac0 : (r == 1) ? ac1 : (r == 2) ? ac2 : ac3;
                float4 h;
                h.x = relu(me.x + p.x + lb.x);
                h.y = relu(me.y + p.y + lb.y);
                h.z = relu(me.z + p.z + lb.z);
                h.w = relu(me.w + p.w + lb.w);
                *(float4*)(&H[(r0l + r) * 256 + c0]) = h;
            }
        }
        __syncthreads();
    }

    // ---- phase 4: t2 = H @ l2_w; C += t2 + l2_b --------------------------
    // thread = (cg 0..31 -> 4 cols, rh 0..1 -> 4 rows, kq 0..3 -> K/4).
    // Partials kq=1,2,3 -> A, Bt, Q.
    {
        const int cg = tid & 31, rh = (tid >> 5) & 1, kq = tid >> 6;
        const int c0 = cg * 4, r0l = rh * 4, k0 = kq * 64;
        float4 ac0 = make_float4(0.f, 0.f, 0.f, 0.f);
        float4 ac1 = make_float4(0.f, 0.f, 0.f, 0.f);
        float4 ac2 = make_float4(0.f, 0.f, 0.f, 0.f);
        float4 ac3 = make_float4(0.f, 0.f, 0.f, 0.f);
#pragma unroll 1
        for (int s = 0; s < 16; ++s) {
            const int kk = k0 + s * 4;
            const float* wp = l2_w + kk * 128 + c0;
            float4 w0 = *(const float4*)(wp);
            float4 w1 = *(const float4*)(wp + 128);
            float4 w2 = *(const float4*)(wp + 256);
            float4 w3 = *(const float4*)(wp + 384);
            float4 a0 = *(const float4*)(&H[(r0l + 0) * 256 + kk]);
            float4 a1 = *(const float4*)(&H[(r0l + 1) * 256 + kk]);
            float4 a2 = *(const float4*)(&H[(r0l + 2) * 256 + kk]);
            float4 a3 = *(const float4*)(&H[(r0l + 3) * 256 + kk]);
            op4(ac0, a0, w0, w1, w2, w3);
            op4(ac1, a1, w0, w1, w2, w3);
            op4(ac2, a2, w0, w1, w2, w3);
            op4(ac3, a3, w0, w1, w2, w3);
        }
        if (kq) {
            float* dst = (kq == 1) ? A : ((kq == 2) ? Bt : Q);
            *(float4*)(&dst[(r0l + 0) * 128 + c0]) = ac0;
            *(float4*)(&dst[(r0l + 1) * 128 + c0]) = ac1;
            *(float4*)(&dst[(r0l + 2) * 128 + c0]) = ac2;
            *(float4*)(&dst[(r0l + 3) * 128 + c0]) = ac3;
        }
        __syncthreads();
        if (kq == 0) {
            float4 lb = *(const float4*)(l2_b + c0);
#pragma unroll
            for (int r = 0; r < 4; ++r) {
                const int base = (r0l + r) * 128 + c0;
                float4 cv = *(const float4*)(&C[base]);
                float4 me = (r == 0) ? ac0 : (r == 1) ? ac1 : (r == 2) ? ac2 : ac3;
                float4 p0 = *(const float4*)(&A[base]);
                float4 p1 = *(const float4*)(&Bt[base]);
                float4 p2 = *(const float4*)(&Q[base]);
                cv.x += lb.x + me.x + p0.x + p1.x + p2.x;
                cv.y += lb.y + me.y + p0.y + p1.y + p2.y;
                cv.z += lb.z + me.z + p0.z + p1.z + p2.z;
                cv.w += lb.w + me.w + p0.w + p1.w + p2.w;
                *(float4*)(&C[base]) = cv;
            }
        }
        __syncthreads();
    }
    ln_rows8(C, n3_g, n3_b, tid);   // C = final tgt
    __syncthreads();

    // ---- phase 5: fused = [F, C] @ fu_w + fu_b; BN partials --------------
    {
        const int c = tid & 63, rg = tid >> 6;
        float acc[2];
        const float fb = fu_b[c];
#pragma unroll
        for (int r = 0; r < 2; ++r) acc[r] = fb;
        const float* wA = fu_w + c;               // rows 0..63 (features half)
#pragma unroll 1
        for (int j4 = 0; j4 < 16; ++j4) {
            float w0 = wA[(j4 * 4 + 0) * 64], w1 = wA[(j4 * 4 + 1) * 64];
            float w2 = wA[(j4 * 4 + 2) * 64], w3 = wA[(j4 * 4 + 3) * 64];
#pragma unroll
            for (int r = 0; r < 2; ++r) {
                float4 t = *(const float4*)(&F[(rg * 2 + r) * 64 + j4 * 4]);
                acc[r] += t.x * w0 + t.y * w1 + t.z * w2 + t.w * w3;
            }
        }
        const float* wB = fu_w + 64 * 64 + c;     // rows 64..191 (tgt half)
#pragma unroll 1
        for (int j4 = 0; j4 < 32; ++j4) {
            float w0 = wB[(j4 * 4 + 0) * 64], w1 = wB[(j4 * 4 + 1) * 64];
            float w2 = wB[(j4 * 4 + 2) * 64], w3 = wB[(j4 * 4 + 3) * 64];
#pragma unroll
            for (int r = 0; r < 2; ++r) {
                float4 t = *(const float4*)(&C[(rg * 2 + r) * 128 + j4 * 4]);
                acc[r] += t.x * w0 + t.y * w1 + t.z * w2 + t.w * w3;
            }
        }
#pragma unroll
        for (int r = 0; r < 2; ++r) {
            int row = rg * 2 + r;
            float v = acc[r];
            fused[(r0 + row) * 64 + c] = v;
            H[row * 64 + c] = v;
        }
    }
    __syncthreads();
    if (tid < 64) {
        float s = 0.f, s2 = 0.f;
#pragma unroll
        for (int r = 0; r < 8; ++r) { float x = H[r * 64 + tid]; s += x; s2 += x * x; }
        atomicAdd(&bnSum[tid], s);
        atomicAdd(&bnSq[tid], s2);
    }
}

// ---------------------------------------------------------------------------
// K5: batchnorm (train-mode stats) + relu -> fp32 out
// ---------------------------------------------------------------------------
__global__ __launch_bounds__(256) void k5_bn_cst(
    const float* __restrict__ fused, const float* __restrict__ bnSum,
    const float* __restrict__ bnSq,
    const float* __restrict__ g, const float* __restrict__ b,
    float* __restrict__ out, int N)
{
    const int total = N * 64;
    const float invN = 1.f / (float)N;
    for (int i = blockIdx.x * 256 + threadIdx.x; i < total; i += gridDim.x * 256) {
        int c = i & 63;
        float mu = bnSum[c] * invN;
        float var = bnSq[c] * invN - mu * mu;
        float x = fused[i];
        float y = (x - mu) * rsqrtf(var + 1e-3f) * g[c] + b[c];
        out[i] = relu(y);
    }
}

// ---------------------------------------------------------------------------
extern "C" void kernel_launch(void* const* d_in, const int* in_sizes, int n_in,
                              void* d_out, int out_size, void* d_ws, size_t ws_size,
                              hipStream_t stream)
{
    const float* features = (const float*)d_in[0];
    const int*   coords   = (const int*)d_in[1];
    const float* pe_w1 = (const float*)d_in[2];
    const float* pe_b1 = (const float*)d_in[3];
    const float* pe_w2 = (const float*)d_in[4];
    const float* pe_b2 = (const float*)d_in[5];
    const float* in_w  = (const float*)d_in[6];
    const float* in_b  = (const float*)d_in[7];
    const float* q_w   = (const float*)d_in[8];
    const float* q_b   = (const float*)d_in[9];
    const float* k_w   = (const float*)d_in[10];
    const float* k_b   = (const float*)d_in[11];
    const float* v_w   = (const float*)d_in[12];
    const float* v_b   = (const float*)d_in[13];
    const float* o_w   = (const float*)d_in[14];
    const float* o_b   = (const float*)d_in[15];
    const float* n1_g  = (const float*)d_in[16];
    const float* n1_b  = (const float*)d_in[17];
    const float* l1_w  = (const float*)d_in[18];
    const float* l1_b  = (const float*)d_in[19];
    const float* l2_w  = (const float*)d_in[20];
    const float* l2_b  = (const float*)d_in[21];
    const float* n3_g  = (const float*)d_in[22];
    const float* n3_b  = (const float*)d_in[23];
    const float* fu_w  = (const float*)d_in[24];
    const float* fu_b  = (const float*)d_in[25];
    const float* bn_g  = (const float*)d_in[26];
    const float* bn_b  = (const float*)d_in[27];

    const int N = in_sizes[0] / 64;   // 8192

    float* src   = (float*)d_ws;            // N*128
    float* qs    = src + (size_t)N * 128;   // N*128
    float* ks    = qs  + (size_t)N * 128;   // N*128
    float* vs    = ks  + (size_t)N * 128;   // N*128
    float* fused = vs  + (size_t)N * 128;   // N*64
    int*   nbr    = (int*)(fused + (size_t)N * 64);   // N*16 ints
    float* bnSum  = (float*)(nbr + (size_t)N * 16);   // 64
    float* bnSq   = bnSum + 64;                       // 64 (contiguous 128)

    ka_pre_cst<<<N / 8 + N / 16, 256, 0, stream>>>(features, coords,
                                                   pe_w1, pe_b1, pe_w2, pe_b2,
                                                   in_w, in_b, q_w, k_w, v_w,
                                                   src, qs, ks, vs, nbr, bnSum, N);
    k4_main_cst<<<N / 8, 256, 0, stream>>>(features, src, qs, ks, vs, nbr,
                                           q_b, k_b, v_b, o_w, o_b, n1_g, n1_b,
                                           l1_w, l1_b, l2_w, l2_b, n3_g, n3_b,
                                           fu_w, fu_b, fused, bnSum, bnSq);
    k5_bn_cst<<<512, 256, 0, stream>>>(fused, bnSum, bnSq, bn_g, bn_b,
                                       (float*)d_out, N);
}